// Round 1
// 73.772 us; speedup vs baseline: 1.0502x; 1.0502x over previous
//
#include <hip/hip_runtime.h>

// NLM smoothing: x[B=8, H=256, W=256, C=8] fp32, K=5, sigma=1, h=1, reflect pad.
//
// v2 changes vs v1 (both verified structure):
//  1. LDS layout AoS -> SoA: v1's tile[pix*2+half] gave a 32 B lane stride on
//     ds_read_b128 (8-bank stride -> only 16/32 banks used, ~8-way conflict,
//     ~2-3x LDS slowdown; LDS is the bottleneck pipe). SoA float4 planes give
//     a 16 B lane stride -> all 32 banks hit evenly -> conflict-free.
//  2. Weight algebra: w ∝ exp(2*c·p - |p|^2 - 0.5*(dr^2+dc^2)); the exp(-|c|^2)
//     factor cancels in the w/sum(w) normalization. |p|^2 is precomputed once
//     per staged pixel into an LDS plane. Inner loop: 27 -> 20 VALU/neighbor.

#define BATCH 8
#define NX 256
#define NY 256
#define HALO 2
#define TSJ 32
#define TSI 8
#define LW (TSJ + 2 * HALO)   // 36
#define LH (TSI + 2 * HALO)   // 12
#define NPIX (LW * LH)        // 432

__device__ __forceinline__ int reflect_idx(int v) {
    // valid for v in [-2, 257] with N=256
    if (v < 0) v = -v;
    if (v > NY - 1) v = 2 * (NY - 1) - v;
    return v;
}

__global__ __launch_bounds__(256) void nlm_kernel(const float4* __restrict__ xv,
                                                  float4* __restrict__ ov) {
    __shared__ float4 t0[NPIX];   // channels 0-3 (conflict-free 16B lane stride)
    __shared__ float4 t1[NPIX];   // channels 4-7
    __shared__ float  tn[NPIX];   // |p|^2 per pixel

    const int t = threadIdx.x;
    const int bj0 = blockIdx.x * TSJ;
    const int bi0 = blockIdx.y * TSI;
    const int b = blockIdx.z;
    const int bbase = b * (NX * NY);

    // ---- stage tile (with reflect halo) into LDS, SoA planes + norms ----
#pragma unroll
    for (int s0 = 0; s0 < NPIX; s0 += 256) {
        const int p = s0 + t;
        if (p < NPIX) {
            const int lr = p / LW;
            const int lc = p - lr * LW;
            const int gi = reflect_idx(bi0 + lr - HALO);
            const int gj = reflect_idx(bj0 + lc - HALO);
            const int gidx = (bbase + gi * NY + gj) * 2;
            const float4 v0 = xv[gidx + 0];
            const float4 v1 = xv[gidx + 1];
            t0[p] = v0;
            t1[p] = v1;
            tn[p] = v0.x * v0.x + v0.y * v0.y + v0.z * v0.z + v0.w * v0.w +
                    v1.x * v1.x + v1.y * v1.y + v1.z * v1.z + v1.w * v1.w;
        }
    }
    __syncthreads();

    // ---- per-thread pixel ----
    const int lj = t & (TSJ - 1);
    const int li = t >> 5;
    const int cpix = (li + HALO) * LW + (lj + HALO);

    const float4 c0 = t0[cpix];
    const float4 c1 = t1[cpix];
    // pre-doubled center for the dot product (2*c . p)
    const float4 cs0 = make_float4(2.f * c0.x, 2.f * c0.y, 2.f * c0.z, 2.f * c0.w);
    const float4 cs1 = make_float4(2.f * c1.x, 2.f * c1.y, 2.f * c1.z, 2.f * c1.w);

    float4 acc0 = make_float4(0.f, 0.f, 0.f, 0.f);
    float4 acc1 = make_float4(0.f, 0.f, 0.f, 0.f);
    float wsum = 0.f;

#pragma unroll
    for (int dr = -HALO; dr <= HALO; ++dr) {
#pragma unroll
        for (int dc = -HALO; dc <= HALO; ++dc) {
            const int pix = cpix + dr * LW + dc;   // constant offset from cpix
            const float4 p0 = t0[pix];
            const float4 p1 = t1[pix];
            const float pn = tn[pix];

            // a = 2*c.p - |p|^2 - 0.5*(dr^2+dc^2)   (exp(-|c|^2) cancels in norm)
            float a = (-0.5f * (float)(dr * dr + dc * dc)) - pn;
            a = fmaf(cs0.x, p0.x, a);
            a = fmaf(cs0.y, p0.y, a);
            a = fmaf(cs0.z, p0.z, a);
            a = fmaf(cs0.w, p0.w, a);
            a = fmaf(cs1.x, p1.x, a);
            a = fmaf(cs1.y, p1.y, a);
            a = fmaf(cs1.z, p1.z, a);
            a = fmaf(cs1.w, p1.w, a);

            const float w = __expf(a);

            acc0.x = fmaf(w, p0.x, acc0.x);
            acc0.y = fmaf(w, p0.y, acc0.y);
            acc0.z = fmaf(w, p0.z, acc0.z);
            acc0.w = fmaf(w, p0.w, acc0.w);
            acc1.x = fmaf(w, p1.x, acc1.x);
            acc1.y = fmaf(w, p1.y, acc1.y);
            acc1.z = fmaf(w, p1.z, acc1.z);
            acc1.w = fmaf(w, p1.w, acc1.w);
            wsum += w;
        }
    }

    const float inv = 1.0f / wsum;
    float4 o0, o1;
    o0.x = acc0.x * inv; o0.y = acc0.y * inv;
    o0.z = acc0.z * inv; o0.w = acc0.w * inv;
    o1.x = acc1.x * inv; o1.y = acc1.y * inv;
    o1.z = acc1.z * inv; o1.w = acc1.w * inv;

    const int oidx = (bbase + (bi0 + li) * NY + (bj0 + lj)) * 2;
    ov[oidx + 0] = o0;
    ov[oidx + 1] = o1;
}

extern "C" void kernel_launch(void* const* d_in, const int* in_sizes, int n_in,
                              void* d_out, int out_size, void* d_ws, size_t ws_size,
                              hipStream_t stream) {
    const float4* x = (const float4*)d_in[0];
    float4* out = (float4*)d_out;
    dim3 grid(NY / TSJ, NX / TSI, BATCH);  // 8 x 32 x 8 = 2048 blocks
    nlm_kernel<<<grid, 256, 0, stream>>>(x, out);
}